// Round 6
// baseline (439.794 us; speedup 1.0000x reference)
//
#include <hip/hip_runtime.h>

#define B_    4
#define N_    50000
#define E_    800000
#define FIN_  128
#define F_    64
#define BN_   (B_ * N_)        // 200000
#define TOT_  (BN_ * F_)       // 12,800,000
#define BE_   (B_ * E_)        // 3,200,000
#define ALPHA_ 0.2f
#define NEG_BIG_ -9.0e15f

#define XS_STRIDE 132
#define GEMM_BLOCKS (BN_ / 64)     // 3125
#define COUNT_BLOCKS (BE_ / 1024)  // 3125 (4 edges/thread)

#define PL_GRID 3128               // 391 slots x 8 XCDs (782 blocks/batch, tail-guarded)
#define GA_GRID 50000              // 6250 slots x 8 XCDs (12500 blocks/batch)

__device__ __forceinline__ float bf2f(unsigned int u16) {
    union { unsigned int i; float f; } v;
    v.i = u16 << 16;
    return v.f;
}
__device__ __forceinline__ unsigned int f2bf(float f) {
    union { float f; unsigned int u; } v;
    v.f = f;
    unsigned int r = v.u + 0x7FFFu + ((v.u >> 16) & 1u);  // RNE
    return r >> 16;
}

// ---- Kernel 1: fused [gemm | count+rank], roles interleaved by bid&1 ------
// (r2-proven form: W staged in LDS; 66KB LDS -> 2 blocks/CU, 147 us)
__global__ __launch_bounds__(256) void gemm_count_kernel(
    const float* __restrict__ X,
    const float* __restrict__ W,
    const float* __restrict__ a,
    const int* __restrict__ edges,
    unsigned short* __restrict__ hq,
    float* __restrict__ e1,
    float* __restrict__ e2,
    int* __restrict__ cnt,
    unsigned short* __restrict__ rank) {
    __shared__ float Wf[FIN_ * F_];            // 32 KB
    __shared__ float Xs[64 * XS_STRIDE];       // 33.8 KB

    const int tid = threadIdx.x;
    const int bid = blockIdx.x;

    if (bid & 1) {
        // ---------------- count role: 4 edges per thread ----------------
        const int g  = (bid >> 1) * 256 + tid;     // 0 .. BE_/4
        const int ge = g * 4;
        const int b  = ge / E_;
        const int e  = ge - b * E_;
        const int4 s4 = *(const int4*)&edges[(size_t)b * 2 * E_ + e];
        ushort4 r4;
        r4.x = (unsigned short)atomicAdd(&cnt[b * N_ + s4.x], 1);
        r4.y = (unsigned short)atomicAdd(&cnt[b * N_ + s4.y], 1);
        r4.z = (unsigned short)atomicAdd(&cnt[b * N_ + s4.z], 1);
        r4.w = (unsigned short)atomicAdd(&cnt[b * N_ + s4.w], 1);
        *(ushort4*)&rank[ge] = r4;
        return;
    }

    // ---------------- gemm role ----------------
    const float4* Wg = (const float4*)W;
    for (int i = tid; i < 2048; i += 256)
        ((float4*)Wf)[i] = Wg[i];

    const int row0 = (bid >> 1) * 64;
    const float4* Xg = (const float4*)(X + (size_t)row0 * FIN_);
    for (int i = tid; i < 2048; i += 256) {
        const int r = i >> 5;
        const int c = i & 31;
        float4 v = Xg[i];
        *(float4*)&Xs[r * XS_STRIDE + c * 4] = v;
    }
    __syncthreads();

    const int cg = tid & 15;
    const int rg = tid >> 4;

    float acc[4][4] = {};
#pragma unroll 4
    for (int k = 0; k < FIN_; ++k) {
        const float4 wv = *(const float4*)&Wf[k * F_ + cg * 4];
        float xr[4];
#pragma unroll
        for (int j = 0; j < 4; ++j)
            xr[j] = Xs[(rg * 4 + j) * XS_STRIDE + k];
#pragma unroll
        for (int j = 0; j < 4; ++j) {
            acc[j][0] += xr[j] * wv.x;
            acc[j][1] += xr[j] * wv.y;
            acc[j][2] += xr[j] * wv.z;
            acc[j][3] += xr[j] * wv.w;
        }
    }

    float a1v[4], a2v[4];
#pragma unroll
    for (int i = 0; i < 4; ++i) {
        a1v[i] = a[cg * 4 + i];
        a2v[i] = a[F_ + cg * 4 + i];
    }

#pragma unroll
    for (int j = 0; j < 4; ++j) {
        const int row = row0 + rg * 4 + j;
        union { ushort4 v; unsigned short s[4]; } st;
#pragma unroll
        for (int i = 0; i < 4; ++i) st.s[i] = (unsigned short)f2bf(acc[j][i]);
        *(ushort4*)&hq[(size_t)row * F_ + cg * 4] = st.v;   // 8B-aligned

        float p1 = acc[j][0] * a1v[0] + acc[j][1] * a1v[1] +
                   acc[j][2] * a1v[2] + acc[j][3] * a1v[3];
        float p2 = acc[j][0] * a2v[0] + acc[j][1] * a2v[1] +
                   acc[j][2] * a2v[2] + acc[j][3] * a2v[3];
#pragma unroll
        for (int m = 8; m >= 1; m >>= 1) {
            p1 += __shfl_xor(p1, m);
            p2 += __shfl_xor(p2, m);
        }
        if (cg == 0) { e1[row] = p1; e2[row] = p2; }
    }
}

// ---- 3-phase multi-block exclusive scan: cnt[BN] -> offs[BN+1] -----------
#define SB_ 196
#define SE_ 1024

__global__ __launch_bounds__(256) void scanA_kernel(
    const int* __restrict__ cnt, int* __restrict__ bsum) {
    __shared__ int red[256];
    const int t = threadIdx.x;
    const int base = blockIdx.x * SE_ + t * 4;
    int s = 0;
    if (base < BN_) {
        const int4 v = *(const int4*)&cnt[base];
        s = v.x + v.y + v.z + v.w;
    }
    red[t] = s;
    __syncthreads();
    for (int off = 128; off >= 1; off >>= 1) {
        if (t < off) red[t] += red[t + off];
        __syncthreads();
    }
    if (t == 0) bsum[blockIdx.x] = red[0];
}

__global__ __launch_bounds__(256) void scanB_kernel(
    const int* __restrict__ bsum, int* __restrict__ boff,
    int* __restrict__ offs) {
    __shared__ int s[256];
    const int t = threadIdx.x;
    const int v = (t < SB_) ? bsum[t] : 0;
    s[t] = v;
    __syncthreads();
    for (int off = 1; off < 256; off <<= 1) {
        const int u = (t >= off) ? s[t - off] : 0;
        __syncthreads();
        s[t] += u;
        __syncthreads();
    }
    if (t < SB_) boff[t] = s[t] - v;
    if (t == SB_ - 1) offs[BN_] = s[t];
}

__global__ __launch_bounds__(256) void scanC_kernel(
    const int* __restrict__ cnt, const int* __restrict__ boff,
    int* __restrict__ offs) {
    __shared__ int s[256];
    const int t = threadIdx.x;
    const int base = blockIdx.x * SE_ + t * 4;
    int4 v = make_int4(0, 0, 0, 0);
    if (base < BN_) v = *(const int4*)&cnt[base];
    const int tot = v.x + v.y + v.z + v.w;
    s[t] = tot;
    __syncthreads();
    for (int off = 1; off < 256; off <<= 1) {
        const int u = (t >= off) ? s[t - off] : 0;
        __syncthreads();
        s[t] += u;
        __syncthreads();
    }
    if (base < BN_) {
        int run = boff[blockIdx.x] + s[t] - tot;
        int4 o;
        o.x = run;
        o.y = run + v.x;
        o.z = o.y + v.y;
        o.w = o.z + v.z;
        *(int4*)&offs[base] = o;
    }
}

// ---- Kernel 4: place, XCD-pinned by batch (batch b -> XCDs {2b,2b+1}). ---
//      atomic-free via rank. 4 edges/thread. csr region/batch = 3.2MB -> L2.
__global__ __launch_bounds__(256) void place_kernel(
    const int* __restrict__ edges,
    const float* __restrict__ e1,
    const float* __restrict__ e2,
    const int* __restrict__ offs,
    const unsigned short* __restrict__ rank,
    unsigned int* __restrict__ csr) {
    const int xcd = blockIdx.x & 7;            // dispatch round-robins XCDs
    const int slot = blockIdx.x >> 3;          // 0..390
    const int b = xcd >> 1;                    // batch pinned to XCD pair
    const int blk = slot * 2 + (xcd & 1);      // 0..781 within batch
    const int e = (blk * 256 + (int)threadIdx.x) * 4;
    if (e >= E_) return;
    const int4 s4 = *(const int4*)&edges[(size_t)b * 2 * E_ + e];
    const int4 d4 = *(const int4*)&edges[(size_t)b * 2 * E_ + E_ + e];
    const ushort4 r4 = *(const ushort4*)&rank[(size_t)b * E_ + e];
    const int ss[4] = { s4.x, s4.y, s4.z, s4.w };
    const int dd[4] = { d4.x, d4.y, d4.z, d4.w };
    const int rr[4] = { r4.x, r4.y, r4.z, r4.w };
#pragma unroll
    for (int j = 0; j < 4; ++j) {
        const int gs = b * N_ + ss[j];
        const float sv = e1[gs] + e2[b * N_ + dd[j]];
        const float lr = sv > 0.0f ? sv : ALPHA_ * sv;
        const float wt = __expf(-lr);
        csr[offs[gs] + rr[j]] = (unsigned int)dd[j] | (f2bf(wt) << 16);
    }
}

// ---- Kernel 5: gather + normalize + elu, XCD-pinned by batch. -------------
//      Wave per node, 4 edge-groups x 16 lanes, uint2/lane, csr 2-deep
//      prefetch. hq slice/batch = 3.2MB -> fits per-XCD L2 (16x dst reuse).
__global__ __launch_bounds__(256) void gather_kernel(
    const int* __restrict__ offs,
    const unsigned int* __restrict__ csr,
    const uint2* __restrict__ hq2,   // packed bf16 quads, [BN][16]
    float* __restrict__ out) {
    const int tid = threadIdx.x;
    const int xcd = blockIdx.x & 7;
    const int slot = blockIdx.x >> 3;          // 0..6249
    const int b = xcd >> 1;                    // batch pinned to XCD pair
    const int blk = slot * 2 + (xcd & 1);      // 0..12499 within batch

    const int lane = tid & 63;
    const int grp = lane >> 4;       // 0..3 edge group
    const int sub = lane & 15;       // 0..15 feature quad
    const int s = (blk * 256 + tid) >> 6;      // 0..49999 (grid exact)
    const int gs = b * N_ + s;
    const uint2* hb = hq2 + (size_t)b * N_ * 16;
    const int k0 = offs[gs];
    const int k1 = offs[gs + 1];

    float a0 = 0.0f, a1 = 0.0f, a2 = 0.0f, a3 = 0.0f, rs = 0.0f;

    int k = k0 + grp;
    unsigned int e_cur = 0u, e_nxt = 0u;
    uint2 p_cur = make_uint2(0u, 0u);
    if (k < k1) e_cur = csr[k];
    if (k + 4 < k1) e_nxt = csr[k + 4];
    if (k < k1) p_cur = hb[(size_t)(e_cur & 0xFFFFu) * 16 + sub];

    for (; k < k1; k += 4) {
        uint2 p_nxt = make_uint2(0u, 0u);
        if (k + 4 < k1) p_nxt = hb[(size_t)(e_nxt & 0xFFFFu) * 16 + sub];
        unsigned int e_nn = 0u;
        if (k + 8 < k1) e_nn = csr[k + 8];

        const float wt = bf2f(e_cur >> 16);
        a0 += wt * bf2f(p_cur.x & 0xFFFFu);
        a1 += wt * bf2f(p_cur.x >> 16);
        a2 += wt * bf2f(p_cur.y & 0xFFFFu);
        a3 += wt * bf2f(p_cur.y >> 16);
        rs += wt;

        e_cur = e_nxt; e_nxt = e_nn; p_cur = p_nxt;
    }

    a0 += __shfl_xor(a0, 16); a1 += __shfl_xor(a1, 16);
    a2 += __shfl_xor(a2, 16); a3 += __shfl_xor(a3, 16);
    rs += __shfl_xor(rs, 16);
    a0 += __shfl_xor(a0, 32); a1 += __shfl_xor(a1, 32);
    a2 += __shfl_xor(a2, 32); a3 += __shfl_xor(a3, 32);
    rs += __shfl_xor(rs, 32);

    if (grp == 0) {
        float v[4];
        v[0] = a0 / rs; v[1] = a1 / rs; v[2] = a2 / rs; v[3] = a3 / rs;
        float4 o;
        float* po = (float*)&o;
#pragma unroll
        for (int j = 0; j < 4; ++j) {
            float x = v[j];
            if (x != x) x = NEG_BIG_;
            po[j] = x > 0.0f ? x : (__expf(x) - 1.0f);
        }
        *(float4*)&out[(size_t)gs * F_ + sub * 4] = o;
    }
}

extern "C" void kernel_launch(void* const* d_in, const int* in_sizes, int n_in,
                              void* d_out, int out_size, void* d_ws, size_t ws_size,
                              hipStream_t stream) {
    const float* X = (const float*)d_in[0];
    const int* edges = (const int*)d_in[1];
    const float* W = (const float*)d_in[2];
    const float* a = (const float*)d_in[3];
    float* out = (float*)d_out;

    // ws layout (~48.0 MB, proven >= 53.6 MB available):
    // [e1 BN f32][e2 BN f32][hq BN*64 bf16][cnt BN i32][offs BN+4 i32]
    // [rank BE u16][csr BE u32][bsum 256][boff 256]
    float* e1 = (float*)d_ws;
    float* e2 = e1 + BN_;
    unsigned short* hq = (unsigned short*)(e2 + BN_);
    int* cnt = (int*)(hq + (size_t)BN_ * F_);
    int* offs = cnt + BN_;
    unsigned short* rank = (unsigned short*)(offs + BN_ + 4);
    unsigned int* csr = (unsigned int*)(rank + BE_);
    int* bsum = (int*)(csr + BE_);
    int* boff = bsum + 256;

    (void)hipMemsetAsync(cnt, 0, (size_t)BN_ * sizeof(int), stream);

    gemm_count_kernel<<<GEMM_BLOCKS + COUNT_BLOCKS, 256, 0, stream>>>(
        X, W, a, edges, hq, e1, e2, cnt, rank);
    scanA_kernel<<<SB_, 256, 0, stream>>>(cnt, bsum);
    scanB_kernel<<<1, 256, 0, stream>>>(bsum, boff, offs);
    scanC_kernel<<<SB_, 256, 0, stream>>>(cnt, boff, offs);
    place_kernel<<<PL_GRID, 256, 0, stream>>>(edges, e1, e2, offs, rank, csr);
    gather_kernel<<<GA_GRID, 256, 0, stream>>>(offs, csr, (const uint2*)hq, out);
}

// Round 7
// 433.442 us; speedup vs baseline: 1.0147x; 1.0147x over previous
//
#include <hip/hip_runtime.h>

#define B_    4
#define N_    50000
#define E_    800000
#define FIN_  128
#define F_    64
#define BN_   (B_ * N_)        // 200000
#define TOT_  (BN_ * F_)       // 12,800,000
#define BE_   (B_ * E_)        // 3,200,000
#define ALPHA_ 0.2f
#define NEG_BIG_ -9.0e15f

#define XS_STRIDE 132
#define GEMM_BLOCKS (BN_ / 64)     // 3125
#define COUNT_BLOCKS (BE_ / 1024)  // 3125 (4 edges/thread)

__device__ __forceinline__ float bf2f(unsigned int u16) {
    union { unsigned int i; float f; } v;
    v.i = u16 << 16;
    return v.f;
}
__device__ __forceinline__ unsigned int f2bf(float f) {
    union { float f; unsigned int u; } v;
    v.f = f;
    unsigned int r = v.u + 0x7FFFu + ((v.u >> 16) & 1u);  // RNE
    return r >> 16;
}

// ---- Kernel 1: fused [gemm | count+rank], roles interleaved by bid&1 ------
// (r2-proven form: W staged in LDS; 66KB LDS -> 2 blocks/CU, ~150 us)
__global__ __launch_bounds__(256) void gemm_count_kernel(
    const float* __restrict__ X,
    const float* __restrict__ W,
    const float* __restrict__ a,
    const int* __restrict__ edges,
    unsigned short* __restrict__ hq,
    float* __restrict__ e1,
    float* __restrict__ e2,
    int* __restrict__ cnt,
    unsigned short* __restrict__ rank) {
    __shared__ float Wf[FIN_ * F_];            // 32 KB
    __shared__ float Xs[64 * XS_STRIDE];       // 33.8 KB

    const int tid = threadIdx.x;
    const int bid = blockIdx.x;

    if (bid & 1) {
        // ---------------- count role: 4 edges per thread ----------------
        const int g  = (bid >> 1) * 256 + tid;     // 0 .. BE_/4
        const int ge = g * 4;
        const int b  = ge / E_;
        const int e  = ge - b * E_;
        const int4 s4 = *(const int4*)&edges[(size_t)b * 2 * E_ + e];
        ushort4 r4;
        r4.x = (unsigned short)atomicAdd(&cnt[b * N_ + s4.x], 1);
        r4.y = (unsigned short)atomicAdd(&cnt[b * N_ + s4.y], 1);
        r4.z = (unsigned short)atomicAdd(&cnt[b * N_ + s4.z], 1);
        r4.w = (unsigned short)atomicAdd(&cnt[b * N_ + s4.w], 1);
        *(ushort4*)&rank[ge] = r4;
        return;
    }

    // ---------------- gemm role ----------------
    const float4* Wg = (const float4*)W;
    for (int i = tid; i < 2048; i += 256)
        ((float4*)Wf)[i] = Wg[i];

    const int row0 = (bid >> 1) * 64;
    const float4* Xg = (const float4*)(X + (size_t)row0 * FIN_);
    for (int i = tid; i < 2048; i += 256) {
        const int r = i >> 5;
        const int c = i & 31;
        float4 v = Xg[i];
        *(float4*)&Xs[r * XS_STRIDE + c * 4] = v;
    }
    __syncthreads();

    const int cg = tid & 15;
    const int rg = tid >> 4;

    float acc[4][4] = {};
#pragma unroll 4
    for (int k = 0; k < FIN_; ++k) {
        const float4 wv = *(const float4*)&Wf[k * F_ + cg * 4];
        float xr[4];
#pragma unroll
        for (int j = 0; j < 4; ++j)
            xr[j] = Xs[(rg * 4 + j) * XS_STRIDE + k];
#pragma unroll
        for (int j = 0; j < 4; ++j) {
            acc[j][0] += xr[j] * wv.x;
            acc[j][1] += xr[j] * wv.y;
            acc[j][2] += xr[j] * wv.z;
            acc[j][3] += xr[j] * wv.w;
        }
    }

    float a1v[4], a2v[4];
#pragma unroll
    for (int i = 0; i < 4; ++i) {
        a1v[i] = a[cg * 4 + i];
        a2v[i] = a[F_ + cg * 4 + i];
    }

#pragma unroll
    for (int j = 0; j < 4; ++j) {
        const int row = row0 + rg * 4 + j;
        union { ushort4 v; unsigned short s[4]; } st;
#pragma unroll
        for (int i = 0; i < 4; ++i) st.s[i] = (unsigned short)f2bf(acc[j][i]);
        *(ushort4*)&hq[(size_t)row * F_ + cg * 4] = st.v;   // 8B-aligned

        float p1 = acc[j][0] * a1v[0] + acc[j][1] * a1v[1] +
                   acc[j][2] * a1v[2] + acc[j][3] * a1v[3];
        float p2 = acc[j][0] * a2v[0] + acc[j][1] * a2v[1] +
                   acc[j][2] * a2v[2] + acc[j][3] * a2v[3];
#pragma unroll
        for (int m = 8; m >= 1; m >>= 1) {
            p1 += __shfl_xor(p1, m);
            p2 += __shfl_xor(p2, m);
        }
        if (cg == 0) { e1[row] = p1; e2[row] = p2; }
    }
}

// ---- 3-phase multi-block exclusive scan: cnt[BN] -> offs[BN+1] -----------
#define SB_ 196
#define SE_ 1024

__global__ __launch_bounds__(256) void scanA_kernel(
    const int* __restrict__ cnt, int* __restrict__ bsum) {
    __shared__ int red[256];
    const int t = threadIdx.x;
    const int base = blockIdx.x * SE_ + t * 4;
    int s = 0;
    if (base < BN_) {
        const int4 v = *(const int4*)&cnt[base];
        s = v.x + v.y + v.z + v.w;
    }
    red[t] = s;
    __syncthreads();
    for (int off = 128; off >= 1; off >>= 1) {
        if (t < off) red[t] += red[t + off];
        __syncthreads();
    }
    if (t == 0) bsum[blockIdx.x] = red[0];
}

__global__ __launch_bounds__(256) void scanB_kernel(
    const int* __restrict__ bsum, int* __restrict__ boff,
    int* __restrict__ offs) {
    __shared__ int s[256];
    const int t = threadIdx.x;
    const int v = (t < SB_) ? bsum[t] : 0;
    s[t] = v;
    __syncthreads();
    for (int off = 1; off < 256; off <<= 1) {
        const int u = (t >= off) ? s[t - off] : 0;
        __syncthreads();
        s[t] += u;
        __syncthreads();
    }
    if (t < SB_) boff[t] = s[t] - v;
    if (t == SB_ - 1) offs[BN_] = s[t];
}

// scanC also packs peg[gs] = {offs[gs], e1[gs]} so place does ONE 8B
// random read instead of two independent 4B reads.
__global__ __launch_bounds__(256) void scanC_kernel(
    const int* __restrict__ cnt, const int* __restrict__ boff,
    const float* __restrict__ e1,
    int* __restrict__ offs,
    int2* __restrict__ peg) {
    __shared__ int s[256];
    const int t = threadIdx.x;
    const int base = blockIdx.x * SE_ + t * 4;
    int4 v = make_int4(0, 0, 0, 0);
    if (base < BN_) v = *(const int4*)&cnt[base];
    const int tot = v.x + v.y + v.z + v.w;
    s[t] = tot;
    __syncthreads();
    for (int off = 1; off < 256; off <<= 1) {
        const int u = (t >= off) ? s[t - off] : 0;
        __syncthreads();
        s[t] += u;
        __syncthreads();
    }
    if (base < BN_) {
        int run = boff[blockIdx.x] + s[t] - tot;
        int4 o;
        o.x = run;
        o.y = run + v.x;
        o.z = o.y + v.y;
        o.w = o.z + v.z;
        *(int4*)&offs[base] = o;
        const float4 ev = *(const float4*)&e1[base];
        int4 pa, pb;
        pa.x = o.x; pa.y = __float_as_int(ev.x);
        pa.z = o.y; pa.w = __float_as_int(ev.y);
        pb.x = o.z; pb.y = __float_as_int(ev.z);
        pb.z = o.w; pb.w = __float_as_int(ev.w);
        int4* pg4 = (int4*)&peg[base];
        pg4[0] = pa;
        pg4[1] = pb;
    }
}

// ---- Kernel 4: place (dst16 | wt_bf16) into CSR slots, ALL batches. ------
//      atomic-free via rank; 3 random transactions/edge: peg(8B) + e2(4B)
//      reads + csr(4B) write. 4 edges/thread.
__global__ __launch_bounds__(256) void place_kernel(
    const int* __restrict__ edges,
    const float* __restrict__ e2,
    const int2* __restrict__ peg,
    const unsigned short* __restrict__ rank,
    unsigned int* __restrict__ csr) {
    const int g  = blockIdx.x * 256 + threadIdx.x;   // grid exact: BE_/1024
    const int ge = g * 4;
    const int b  = ge / E_;
    const int e  = ge - b * E_;
    const int4 s4 = *(const int4*)&edges[(size_t)b * 2 * E_ + e];
    const int4 d4 = *(const int4*)&edges[(size_t)b * 2 * E_ + E_ + e];
    const ushort4 r4 = *(const ushort4*)&rank[ge];
    const int ss[4] = { s4.x, s4.y, s4.z, s4.w };
    const int dd[4] = { d4.x, d4.y, d4.z, d4.w };
    const int rr[4] = { r4.x, r4.y, r4.z, r4.w };
#pragma unroll
    for (int j = 0; j < 4; ++j) {
        const int2 pg = peg[b * N_ + ss[j]];
        const float sv = __int_as_float(pg.y) + e2[b * N_ + dd[j]];
        const float lr = sv > 0.0f ? sv : ALPHA_ * sv;
        const float wt = __expf(-lr);
        csr[pg.x + rr[j]] = (unsigned int)dd[j] | (f2bf(wt) << 16);
    }
}

// ---- Kernel 5: gather + normalize + elu, ALL batches. Wave per node. -----
// 4 edge-groups x 16 lanes, uint2/lane; csr 3-deep + hq 2-deep prefetch so
// each hq row is consumed TWO iterations after issue (latency overlap 2x).
__global__ __launch_bounds__(256) void gather_kernel(
    const int* __restrict__ offs,
    const unsigned int* __restrict__ csr,
    const uint2* __restrict__ hq2,   // packed bf16 quads, [BN][16]
    float* __restrict__ out) {
    const int tid = threadIdx.x;
    const int lane = tid & 63;
    const int grp = lane >> 4;       // 0..3 edge group
    const int sub = lane & 15;       // 0..15 feature quad
    const int gs = (int)((blockIdx.x * 256 + tid) >> 6);  // 0..BN_ (exact)
    const int b = gs / N_;
    const uint2* hb = hq2 + (size_t)b * N_ * 16;
    const int k0 = offs[gs];
    const int k1 = offs[gs + 1];

    float a0 = 0.0f, a1 = 0.0f, a2 = 0.0f, a3 = 0.0f, rs = 0.0f;

    int k = k0 + grp;
    unsigned int e0 = 0u, e1v = 0u, e2v = 0u;
    uint2 p0 = make_uint2(0u, 0u), p1 = make_uint2(0u, 0u);
    if (k < k1)     e0  = csr[k];
    if (k + 4 < k1) e1v = csr[k + 4];
    if (k + 8 < k1) e2v = csr[k + 8];
    if (k < k1)     p0 = hb[(size_t)(e0 & 0xFFFFu) * 16 + sub];
    if (k + 4 < k1) p1 = hb[(size_t)(e1v & 0xFFFFu) * 16 + sub];

    for (; k < k1; k += 4) {
        uint2 pn = make_uint2(0u, 0u);
        if (k + 8 < k1) pn = hb[(size_t)(e2v & 0xFFFFu) * 16 + sub];
        unsigned int en = 0u;
        if (k + 12 < k1) en = csr[k + 12];

        const float wt = bf2f(e0 >> 16);
        a0 += wt * bf2f(p0.x & 0xFFFFu);
        a1 += wt * bf2f(p0.x >> 16);
        a2 += wt * bf2f(p0.y & 0xFFFFu);
        a3 += wt * bf2f(p0.y >> 16);
        rs += wt;

        e0 = e1v; e1v = e2v; e2v = en;
        p0 = p1; p1 = pn;
    }

    a0 += __shfl_xor(a0, 16); a1 += __shfl_xor(a1, 16);
    a2 += __shfl_xor(a2, 16); a3 += __shfl_xor(a3, 16);
    rs += __shfl_xor(rs, 16);
    a0 += __shfl_xor(a0, 32); a1 += __shfl_xor(a1, 32);
    a2 += __shfl_xor(a2, 32); a3 += __shfl_xor(a3, 32);
    rs += __shfl_xor(rs, 32);

    if (grp == 0) {
        float v[4];
        v[0] = a0 / rs; v[1] = a1 / rs; v[2] = a2 / rs; v[3] = a3 / rs;
        float4 o;
        float* po = (float*)&o;
#pragma unroll
        for (int j = 0; j < 4; ++j) {
            float x = v[j];
            if (x != x) x = NEG_BIG_;
            po[j] = x > 0.0f ? x : (__expf(x) - 1.0f);
        }
        *(float4*)&out[(size_t)gs * F_ + sub * 4] = o;
    }
}

extern "C" void kernel_launch(void* const* d_in, const int* in_sizes, int n_in,
                              void* d_out, int out_size, void* d_ws, size_t ws_size,
                              hipStream_t stream) {
    const float* X = (const float*)d_in[0];
    const int* edges = (const int*)d_in[1];
    const float* W = (const float*)d_in[2];
    const float* a = (const float*)d_in[3];
    float* out = (float*)d_out;

    // ws layout (~49.6 MB, proven >= 53.6 MB available):
    // [e1 BN f32][e2 BN f32][hq BN*64 bf16][cnt BN i32][offs BN+4 i32]
    // [rank BE u16][csr BE u32][bsum 256][boff 256][peg BN int2]
    float* e1 = (float*)d_ws;
    float* e2 = e1 + BN_;
    unsigned short* hq = (unsigned short*)(e2 + BN_);
    int* cnt = (int*)(hq + (size_t)BN_ * F_);
    int* offs = cnt + BN_;
    unsigned short* rank = (unsigned short*)(offs + BN_ + 4);
    unsigned int* csr = (unsigned int*)(rank + BE_);
    int* bsum = (int*)(csr + BE_);
    int* boff = bsum + 256;
    int2* peg = (int2*)(boff + 256);

    (void)hipMemsetAsync(cnt, 0, (size_t)BN_ * sizeof(int), stream);

    gemm_count_kernel<<<GEMM_BLOCKS + COUNT_BLOCKS, 256, 0, stream>>>(
        X, W, a, edges, hq, e1, e2, cnt, rank);
    scanA_kernel<<<SB_, 256, 0, stream>>>(cnt, bsum);
    scanB_kernel<<<1, 256, 0, stream>>>(bsum, boff, offs);
    scanC_kernel<<<SB_, 256, 0, stream>>>(cnt, boff, e1, offs, peg);
    place_kernel<<<BE_ / 1024, 256, 0, stream>>>(edges, e2, peg, rank, csr);
    gather_kernel<<<BN_ / 4, 256, 0, stream>>>(offs, csr, (const uint2*)hq, out);
}